// Round 9
// baseline (256.651 us; speedup 1.0000x reference)
//
#include <hip/hip_runtime.h>
#include <hip/hip_bf16.h>

#define N_NODES 50000
#define N_EDGES 800000
#define F_IN 32
#define CELL_DIM 16
#define D_IN 48      // F_IN + CELL_DIM
#define X_STRIDE 33  // F_IN + 1 (cell id column)
#define NUM_CELLS 854
#define NEG_SLOPE 0.2f
#define NODE0_BLOCKS 2048  // persistent node0 blocks (8 nodes per block-iteration)
#define EDGE_BLOCKS 3125   // ceil(800000/256) bucket-fill blocks
#define NXCD 8
#define BWX 16             // per-XCD bucket width; per-(node,XCD) ~Poisson(2), P(>=16)~2e-10
#define W 24               // edge window per latency round

typedef unsigned int uint;
typedef unsigned short ushort;

// f32 -> bf16 bits, round-to-nearest-even
static __device__ __forceinline__ uint f2b(float f) {
  uint x = __float_as_uint(f);
  return (x + 0x7fffu + ((x >> 16) & 1u)) >> 16;
}
static __device__ __forceinline__ float b2f_lo(uint w) { return __uint_as_float(w << 16); }
static __device__ __forceinline__ float b2f_hi(uint w) { return __uint_as_float(w & 0xffff0000u); }
// lrelu(e) = max(e, 0.2e): valid for both signs since 0 < slope < 1 (2 VALU, no cndmask)
static __device__ __forceinline__ float lrelu(float e) { return fmaxf(e, NEG_SLOPE * e); }

// ---------------- Node0 dense part (split out for attribution; body unchanged) ----------------

__global__ __launch_bounds__(256) void k_node0(const float* __restrict__ x,
                                               const float* __restrict__ emb,
                                               const float* __restrict__ W0,
                                               const float* __restrict__ asrc,
                                               const float* __restrict__ adst,
                                               ushort* __restrict__ h0u,
                                               float* __restrict__ as0, float* __restrict__ ad0) {
  int tid = threadIdx.x;
  __shared__ float hin[8][48];  // 8 node rows; float4 reads are wave-uniform (broadcast)
  int lane = tid & 63, wid = tid >> 6;
  int h = wid & 1;       // head
  int q = wid >> 1;      // node-quad (0: nodes 0-3, 1: nodes 4-7)
  float w0r[D_IN];       // 48 VGPRs: this head's W0 column for channel `lane`
#pragma unroll
  for (int k = 0; k < D_IN; ++k) w0r[k] = W0[k * 128 + h * 64 + lane];
  float av_s = asrc[h * 64 + lane], av_d = adst[h * 64 + lane];

  for (int g = blockIdx.x; g < N_NODES / 8; g += NODE0_BLOCKS) {
    int nb = g * 8;
    // stage: wave w stages rows 2w, 2w+1
#pragma unroll
    for (int j = 0; j < 2; ++j) {
      int loc = 2 * wid + j;
      int n = nb + loc;
      float t = 0.f;
      if (lane < 33) t = x[n * X_STRIDE + lane];
      int cid = (int)__shfl(t, 32, 64);
      cid = cid < 0 ? 0 : (cid >= NUM_CELLS ? NUM_CELLS - 1 : cid);  // fault guard
      if (lane >= 32 && lane < 48) t = emb[cid * CELL_DIM + (lane - 32)];
      if (lane < 48) hin[loc][lane] = t;
    }
    __syncthreads();
    // compute: 4 nodes of my quad, my head, channel = lane
#pragma unroll
    for (int j = 0; j < 4; ++j) {
      int loc = 4 * q + j;
      int n = nb + loc;
      const float4* hp = (const float4*)hin[loc];
      float acc = 0.f;
#pragma unroll
      for (int k4 = 0; k4 < 12; ++k4) {
        float4 hh = hp[k4];
        acc = fmaf(hh.x, w0r[4 * k4 + 0], acc);
        acc = fmaf(hh.y, w0r[4 * k4 + 1], acc);
        acc = fmaf(hh.z, w0r[4 * k4 + 2], acc);
        acc = fmaf(hh.w, w0r[4 * k4 + 3], acc);
      }
      h0u[(n * 64 + lane) * 2 + h] = (ushort)f2b(acc);  // packed half of the bf16x2 word
      float sa = acc * av_s, sd = acc * av_d;
#pragma unroll
      for (int o = 32; o >= 1; o >>= 1) {
        sa += __shfl_xor(sa, o, 64);
        sd += __shfl_xor(sd, o, 64);
      }
      if (lane == 0) {
        as0[n * 2 + h] = sa;  // float2-compatible layout {head0, head1}
        ad0[n * 2 + h] = sd;
      }
    }
    __syncthreads();  // before restaging
  }
}

// ---------------- Bucket fill, XCD-private ----------------
// R19: each XCD fills its OWN cnt/bkt copy (selected via HW_REG_XCC_ID). Atomics and
// stores from one XCD touch only its private 1.6MB region -> lines stay resident in that
// XCD's L2 (no cross-XCD ownership ping-pong, which R17/R18 measured as ~50MB of
// line-granular write amplification). Correctness is XCD-assignment independent: any
// consistent copy index works; agg kernels sum all 8 sublists.

__global__ __launch_bounds__(256) void k_bfill(const int* __restrict__ ei,
                                               int* __restrict__ cnt,
                                               ushort* __restrict__ bkt) {
  int e = blockIdx.x * 256 + threadIdx.x;
  if (e >= N_EDGES) return;
  uint xcc;
  asm volatile("s_getreg_b32 %0, hwreg(HW_REG_XCC_ID)" : "=s"(xcc));
  xcc &= (NXCD - 1);
  int s = ei[e], d = ei[N_EDGES + e];
  int p = atomicAdd(&cnt[xcc * N_NODES + d], 1);
  if (p < BWX) bkt[(xcc * N_NODES + d) * BWX + p] = (ushort)s;  // overflow (never) drops
}

// ---------------- sublist-concat helpers (agg kernels) ----------------
// Per node: 8 per-XCD sublists of lengths c[x] (<=BWX). Wave computes the inclusive scan
// of c over lanes 0..7 once; each lane maps its item idx -> (sublist x, offset) via a
// 7-compare select chain against the node-uniform prefixes p1..p7 (pure VALU, no LDS).

// ---------------- Fused aggregate L0 (+LN+ELU+linear1+alpha1) ----------------

__global__ __launch_bounds__(256) void k_agg0(const int* __restrict__ cnt,
                                              const ushort* __restrict__ bkt,
                                              const float2* __restrict__ as0v,
                                              const float2* __restrict__ ad0v,
                                              const uint* __restrict__ h0p,
                                              const float* __restrict__ b0,
                                              const float* __restrict__ lng,
                                              const float* __restrict__ lnb,
                                              const float* __restrict__ W1,
                                              const float* __restrict__ asrc1,
                                              const float* __restrict__ adst1,
                                              ushort* __restrict__ h1b,
                                              float* __restrict__ as1, float* __restrict__ ad1) {
  __shared__ uint gbuf[4][W * 64];  // per-wave gather landing zone (W rows x 256B)
  __shared__ float yb[4][64];       // wave-private y row for linear1 broadcasts
  int tid = threadIdx.x;
  int lane = tid & 63, wl = tid >> 6;
  int n = blockIdx.x * 4 + wl;
  // 8 sublist lengths + inclusive scan on lanes 0..7
  int cx = 0;
  if (lane < 8) cx = min(cnt[lane * N_NODES + n], BWX);
  int sc = cx;
#pragma unroll
  for (int o = 1; o < 8; o <<= 1) {
    int t = __shfl_up(sc, o, 64);
    if (lane >= o) sc += t;  // lanes >=8 hold garbage; unused
  }
  int p1 = __shfl(sc, 0, 64), p2 = __shfl(sc, 1, 64), p3 = __shfl(sc, 2, 64);
  int p4 = __shfl(sc, 3, 64), p5 = __shfl(sc, 4, 64), p6 = __shfl(sc, 5, 64);
  int p7 = __shfl(sc, 6, 64);
  int total = __shfl(sc, 7, 64);
  int items = total + 1;  // + self item at idx == total

  float2 ad = ad0v[n];
  float acc0 = 0.f, acc1 = 0.f, den0 = 0.f, den1 = 0.f;
  uint* gb = gbuf[wl];

  for (int w0 = 0; w0 < items; w0 += W) {
    int idx = w0 + lane;
    // map idx -> (sublist x, base prefix) via select chain (node-uniform thresholds)
    int xsl = (idx >= p1) + (idx >= p2) + (idx >= p3) + (idx >= p4) +
              (idx >= p5) + (idx >= p6) + (idx >= p7);
    int base = xsl == 0 ? 0 : (xsl == 1 ? p1 : (xsl == 2 ? p2 : (xsl == 3 ? p3 :
               (xsl == 4 ? p4 : (xsl == 5 ? p5 : (xsl == 6 ? p6 : p7))))));
    uint sl = (uint)bkt[xsl * (N_NODES * BWX) + n * BWX + (idx - base)];  // over-read ok
    uint s = (idx < total) ? sl : (uint)n;  // self item + padding lanes -> n (hot row)
    float wv0 = 0.f, wv1 = 0.f;             // padded lanes contribute exactly 0
    if (lane < W && idx < items) {
      float2 a = as0v[s];  // L2-resident gather
      wv0 = __expf(lrelu(a.x + ad.x));
      wv1 = __expf(lrelu(a.y + ad.y));
    }
    // issue all W gathers into LDS (no VGPR destinations)
#pragma unroll
    for (int j = 0; j < W; ++j) {
      uint sx = (uint)__builtin_amdgcn_readlane((int)s, j);  // SGPR row index
      __builtin_amdgcn_global_load_lds((const uint*)(h0p + sx * 64u + (uint)lane),
                                       gb + j * 64, 4, 0, 0);
    }
    asm volatile("s_waitcnt vmcnt(0)" ::: "memory");
    __builtin_amdgcn_sched_barrier(0);
#pragma unroll
    for (int j = 0; j < W; ++j) {
      float w0j = __uint_as_float(
          (uint)__builtin_amdgcn_readlane((int)__float_as_uint(wv0), j));
      float w1j = __uint_as_float(
          (uint)__builtin_amdgcn_readlane((int)__float_as_uint(wv1), j));
      uint h = gb[j * 64 + lane];
      acc0 = fmaf(w0j, b2f_lo(h), acc0); den0 += w0j;
      acc1 = fmaf(w1j, b2f_hi(h), acc1); den1 += w1j;
    }
    asm volatile("s_waitcnt lgkmcnt(0)" ::: "memory");  // drain LDS reads before gbuf reuse
    __builtin_amdgcn_sched_barrier(0);
  }

  float v = 0.5f * (acc0 / den0 + acc1 / den1) + b0[lane];
  // LayerNorm across the 64 channels (one wave)
  float mu = v;
#pragma unroll
  for (int o = 32; o >= 1; o >>= 1) mu += __shfl_xor(mu, o, 64);
  mu *= (1.0f / 64.0f);
  float d = v - mu;
  float vr = d * d;
#pragma unroll
  for (int o = 32; o >= 1; o >>= 1) vr += __shfl_xor(vr, o, 64);
  vr *= (1.0f / 64.0f);
  float y = d * rsqrtf(vr + 1e-5f) * lng[lane] + lnb[lane];
  // ELU
  y = y > 0.f ? y : expm1f(y);
  // linear1 via LDS broadcast: h1[c] = sum_k y_k * W1[k,c], 4 partial accumulators.
  yb[wl][lane] = y;
  const float4* yp = (const float4*)yb[wl];
  float q0 = 0.f, q1 = 0.f, q2 = 0.f, q3 = 0.f;
#pragma unroll
  for (int k4 = 0; k4 < 16; ++k4) {
    float4 yy = yp[k4];  // wave-uniform address -> LDS broadcast, conflict-free
    q0 = fmaf(yy.x, W1[(4 * k4 + 0) * 64 + lane], q0);
    q1 = fmaf(yy.y, W1[(4 * k4 + 1) * 64 + lane], q1);
    q2 = fmaf(yy.z, W1[(4 * k4 + 2) * 64 + lane], q2);
    q3 = fmaf(yy.w, W1[(4 * k4 + 3) * 64 + lane], q3);
  }
  float h1v = (q0 + q1) + (q2 + q3);
  h1b[n * 64 + lane] = (ushort)f2b(h1v);
  float sa = h1v * asrc1[lane];
  float sdv = h1v * adst1[lane];
#pragma unroll
  for (int o = 32; o >= 1; o >>= 1) {
    sa += __shfl_xor(sa, o, 64);
    sdv += __shfl_xor(sdv, o, 64);
  }
  if (lane == 0) {
    as1[n] = sa;
    ad1[n] = sdv;
  }
}

// ---------------- Layer 1 aggregate -> output ----------------

__global__ __launch_bounds__(256) void k_agg1(const int* __restrict__ cnt,
                                              const ushort* __restrict__ bkt,
                                              const ushort* __restrict__ h1b,
                                              const float* __restrict__ as1,
                                              const float* __restrict__ ad1,
                                              const float* __restrict__ b1,
                                              float* __restrict__ out) {
  __shared__ uint gbuf[4][W * 64];
  int tid = threadIdx.x;
  int lane = tid & 63, wl = tid >> 6;
  int n = blockIdx.x * 4 + wl;
  int cx = 0;
  if (lane < 8) cx = min(cnt[lane * N_NODES + n], BWX);
  int sc = cx;
#pragma unroll
  for (int o = 1; o < 8; o <<= 1) {
    int t = __shfl_up(sc, o, 64);
    if (lane >= o) sc += t;
  }
  int p1 = __shfl(sc, 0, 64), p2 = __shfl(sc, 1, 64), p3 = __shfl(sc, 2, 64);
  int p4 = __shfl(sc, 3, 64), p5 = __shfl(sc, 4, 64), p6 = __shfl(sc, 5, 64);
  int p7 = __shfl(sc, 6, 64);
  int total = __shfl(sc, 7, 64);
  int items = total + 1;

  float adv = ad1[n];
  float acc = 0.f, den = 0.f;
  uint* gb = gbuf[wl];
  const ushort* gbs = (const ushort*)gb;

  for (int w0 = 0; w0 < items; w0 += W) {
    int idx = w0 + lane;
    int xsl = (idx >= p1) + (idx >= p2) + (idx >= p3) + (idx >= p4) +
              (idx >= p5) + (idx >= p6) + (idx >= p7);
    int base = xsl == 0 ? 0 : (xsl == 1 ? p1 : (xsl == 2 ? p2 : (xsl == 3 ? p3 :
               (xsl == 4 ? p4 : (xsl == 5 ? p5 : (xsl == 6 ? p6 : p7))))));
    uint sl = (uint)bkt[xsl * (N_NODES * BWX) + n * BWX + (idx - base)];
    uint s = (idx < total) ? sl : (uint)n;
    float wv = 0.f;
    if (lane < W && idx < items) {
      wv = __expf(lrelu(as1[s] + adv));  // one exp per lane, not per edge
    }
    uint hl = lane & 31;  // lanes 32-63 duplicate lanes 0-31 (same cache lines)
#pragma unroll
    for (int j = 0; j < W; ++j) {
      uint sx = (uint)__builtin_amdgcn_readlane((int)s, j);
      __builtin_amdgcn_global_load_lds((const uint*)(h1b + sx * 64u) + hl,
                                       gb + j * 64, 4, 0, 0);
    }
    asm volatile("s_waitcnt vmcnt(0)" ::: "memory");
    __builtin_amdgcn_sched_barrier(0);
#pragma unroll
    for (int j = 0; j < W; ++j) {
      float wj = __uint_as_float(
          (uint)__builtin_amdgcn_readlane((int)__float_as_uint(wv), j));
      uint hh = (uint)gbs[j * 128 + lane];  // valid first 128B of the slot
      acc = fmaf(wj, __uint_as_float(hh << 16), acc);
      den += wj;
    }
    asm volatile("s_waitcnt lgkmcnt(0)" ::: "memory");
    __builtin_amdgcn_sched_barrier(0);
  }
  out[n * 64 + lane] = acc / den + b1[lane];
}

// ---------------- host ----------------

extern "C" void kernel_launch(void* const* d_in, const int* in_sizes, int n_in,
                              void* d_out, int out_size, void* d_ws, size_t ws_size,
                              hipStream_t stream) {
  const float* x    = (const float*)d_in[0];
  const int*   ei   = (const int*)d_in[1];
  const float* emb  = (const float*)d_in[2];
  const float* W0   = (const float*)d_in[3];
  const float* as0w = (const float*)d_in[4];
  const float* ad0w = (const float*)d_in[5];
  const float* b0   = (const float*)d_in[6];
  const float* lng  = (const float*)d_in[7];
  const float* lnb  = (const float*)d_in[8];
  const float* W1   = (const float*)d_in[9];
  const float* as1w = (const float*)d_in[10];
  const float* ad1w = (const float*)d_in[11];
  const float* b1   = (const float*)d_in[12];
  float* out = (float*)d_out;

  // workspace layout (~34.8 MB): XCD-private bkt (8x) + cnt (8x)
  ushort* bkt = (ushort*)d_ws;                     // 8*N*BWX ushorts = 12.8MB
  int* cnt   = (int*)(bkt + NXCD * N_NODES * BWX); // 8*N ints = 1.6MB
  float* as0 = (float*)(cnt + NXCD * N_NODES);     // N*2 (float2 per node)
  float* ad0 = as0 + N_NODES * 2;                  // N*2
  float* as1 = ad0 + N_NODES * 2;                  // N
  float* ad1 = as1 + N_NODES;                      // N
  uint* h0p  = (uint*)(ad1 + N_NODES);             // N*64 (bf16x2 packed) = 12.8MB
  ushort* h1b = (ushort*)(h0p + N_NODES * 64);     // N*64 bf16 = 6.4MB

  hipMemsetAsync(cnt, 0, NXCD * N_NODES * sizeof(int), stream);
  k_bfill<<<EDGE_BLOCKS, 256, 0, stream>>>(ei, cnt, bkt);
  k_node0<<<NODE0_BLOCKS, 256, 0, stream>>>(x, emb, W0, as0w, ad0w, (ushort*)h0p, as0, ad0);
  k_agg0<<<N_NODES / 4, 256, 0, stream>>>(cnt, bkt, (const float2*)as0, (const float2*)ad0,
                                          h0p, b0, lng, lnb, W1, as1w, ad1w, h1b, as1, ad1);
  k_agg1<<<N_NODES / 4, 256, 0, stream>>>(cnt, bkt, h1b, as1, ad1, b1, out);
}

// Round 10
// 251.879 us; speedup vs baseline: 1.0189x; 1.0189x over previous
//
#include <hip/hip_runtime.h>
#include <hip/hip_bf16.h>

#define N_NODES 50000
#define N_EDGES 800000
#define F_IN 32
#define CELL_DIM 16
#define D_IN 48      // F_IN + CELL_DIM
#define X_STRIDE 33  // F_IN + 1 (cell id column)
#define NUM_CELLS 854
#define NEG_SLOPE 0.2f
#define NODE0_BLOCKS 2048  // persistent node0 blocks (8 nodes per block-iteration)
#define MERGE_BLOCKS 1563  // ceil(50000/32) merge tail blocks (32 nodes/block, 8 lanes/node)
#define EDGE_BLOCKS 3125   // ceil(800000/256) bucket-fill blocks
#define NXCD 8
#define BWX 16             // per-XCD bucket width; per-(node,XCD) ~Poisson(2), P(>=16)~2e-10
#define BW 48              // compact bucket width; P(deg>=48 | ~Poisson(16)) ~ 1e-10
#define W 24               // edge window per latency round

typedef unsigned int uint;
typedef unsigned short ushort;

// f32 -> bf16 bits, round-to-nearest-even
static __device__ __forceinline__ uint f2b(float f) {
  uint x = __float_as_uint(f);
  return (x + 0x7fffu + ((x >> 16) & 1u)) >> 16;
}
static __device__ __forceinline__ float b2f_lo(uint w) { return __uint_as_float(w << 16); }
static __device__ __forceinline__ float b2f_hi(uint w) { return __uint_as_float(w & 0xffff0000u); }
// lrelu(e) = max(e, 0.2e): valid for both signs since 0 < slope < 1 (2 VALU, no cndmask)
static __device__ __forceinline__ float lrelu(float e) { return fmaxf(e, NEG_SLOPE * e); }

// ---------------- Bucket fill, XCD-private (R19, kept) ----------------
// Each XCD fills its OWN cnt/bkt copy (HW_REG_XCC_ID) -> no cross-XCD line ping-pong.
// Correctness is XCD-assignment independent (any consistent copy works; merge sums all 8).

__global__ __launch_bounds__(256) void k_bfill(const int* __restrict__ ei,
                                               int* __restrict__ cnt,
                                               ushort* __restrict__ bkt) {
  int e = blockIdx.x * 256 + threadIdx.x;
  if (e >= N_EDGES) return;
  uint xcc;
  asm volatile("s_getreg_b32 %0, hwreg(HW_REG_XCC_ID)" : "=s"(xcc));
  xcc &= (NXCD - 1);
  int s = ei[e], d = ei[N_EDGES + e];
  int p = atomicAdd(&cnt[xcc * N_NODES + d], 1);
  if (p < BWX) bkt[(xcc * N_NODES + d) * BWX + p] = (ushort)s;  // overflow (never) drops
}

// ---------------- Node0 dense part + sublist merge tail ----------------
// blocks < NODE0_BLOCKS: unchanged known-good node0 compute.
// blocks >= NODE0_BLOCKS: merge — one 8-lane group per node concatenates the 8 XCD-private
// sublists into a contiguous bktc row + cntc count. Reads are n-contiguous per region;
// writes are clustered per node (1-2 lines by one wave -> L2 merges, no scatter write-amp).
// Runs in the same launch as node0 -> overlaps its compute-bound drain.

__global__ __launch_bounds__(256) void k_node0(const float* __restrict__ x,
                                               const float* __restrict__ emb,
                                               const float* __restrict__ W0,
                                               const float* __restrict__ asrc,
                                               const float* __restrict__ adst,
                                               const int* __restrict__ cnt,
                                               const ushort* __restrict__ bkt,
                                               ushort* __restrict__ h0u,
                                               float* __restrict__ as0, float* __restrict__ ad0,
                                               int* __restrict__ cntc,
                                               ushort* __restrict__ bktc) {
  int tid = threadIdx.x;
  if (blockIdx.x >= NODE0_BLOCKS) {  // ---- merge tail ----
    int n = (blockIdx.x - NODE0_BLOCKS) * 32 + (tid >> 3);
    if (n >= N_NODES) return;
    int xg = tid & 7;  // this lane's XCD sublist
    int cx = min(cnt[xg * N_NODES + n], BWX);
    int sc = cx;  // inclusive scan within the aligned 8-lane group
#pragma unroll
    for (int o = 1; o < 8; o <<= 1) {
      int t = __shfl_up(sc, o, 64);
      if ((tid & 7) >= o) sc += t;
    }
    int total = __shfl(sc, (tid & 63) | 7, 64);  // group's last lane
    int base = sc - cx;                          // exclusive prefix
    const ushort* src = bkt + (xg * N_NODES + n) * BWX;
    for (int k = 0; k < cx; ++k) {
      int slot = base + k;
      if (slot < BW) bktc[n * BW + slot] = src[k];
    }
    if (xg == 7) cntc[n] = min(total, BW);
    return;
  }
  // ---- node0 compute (unchanged, known-good) ----
  __shared__ float hin[8][48];  // 8 node rows; float4 reads are wave-uniform (broadcast)
  int lane = tid & 63, wid = tid >> 6;
  int h = wid & 1;       // head
  int q = wid >> 1;      // node-quad (0: nodes 0-3, 1: nodes 4-7)
  float w0r[D_IN];       // 48 VGPRs: this head's W0 column for channel `lane`
#pragma unroll
  for (int k = 0; k < D_IN; ++k) w0r[k] = W0[k * 128 + h * 64 + lane];
  float av_s = asrc[h * 64 + lane], av_d = adst[h * 64 + lane];

  for (int g = blockIdx.x; g < N_NODES / 8; g += NODE0_BLOCKS) {
    int nb = g * 8;
    // stage: wave w stages rows 2w, 2w+1
#pragma unroll
    for (int j = 0; j < 2; ++j) {
      int loc = 2 * wid + j;
      int n = nb + loc;
      float t = 0.f;
      if (lane < 33) t = x[n * X_STRIDE + lane];
      int cid = (int)__shfl(t, 32, 64);
      cid = cid < 0 ? 0 : (cid >= NUM_CELLS ? NUM_CELLS - 1 : cid);  // fault guard
      if (lane >= 32 && lane < 48) t = emb[cid * CELL_DIM + (lane - 32)];
      if (lane < 48) hin[loc][lane] = t;
    }
    __syncthreads();
    // compute: 4 nodes of my quad, my head, channel = lane
#pragma unroll
    for (int j = 0; j < 4; ++j) {
      int loc = 4 * q + j;
      int n = nb + loc;
      const float4* hp = (const float4*)hin[loc];
      float acc = 0.f;
#pragma unroll
      for (int k4 = 0; k4 < 12; ++k4) {
        float4 hh = hp[k4];
        acc = fmaf(hh.x, w0r[4 * k4 + 0], acc);
        acc = fmaf(hh.y, w0r[4 * k4 + 1], acc);
        acc = fmaf(hh.z, w0r[4 * k4 + 2], acc);
        acc = fmaf(hh.w, w0r[4 * k4 + 3], acc);
      }
      h0u[(n * 64 + lane) * 2 + h] = (ushort)f2b(acc);  // packed half of the bf16x2 word
      float sa = acc * av_s, sd = acc * av_d;
#pragma unroll
      for (int o = 32; o >= 1; o >>= 1) {
        sa += __shfl_xor(sa, o, 64);
        sd += __shfl_xor(sd, o, 64);
      }
      if (lane == 0) {
        as0[n * 2 + h] = sa;  // float2-compatible layout {head0, head1}
        ad0[n * 2 + h] = sd;
      }
    }
    __syncthreads();  // before restaging
  }
}

// ---------------- Fused aggregate L0 (+LN+ELU+linear1+alpha1) ----------------
// R18's exact passing structure (compact bucket): per-lane weight compute (one exp pair
// per lane per window), W global_load_lds gathers (zero VGPR dests), accumulate from LDS
// with readlane-broadcast f32 weights.

__global__ __launch_bounds__(256) void k_agg0(const int* __restrict__ cnt,
                                              const ushort* __restrict__ bkt,
                                              const float2* __restrict__ as0v,
                                              const float2* __restrict__ ad0v,
                                              const uint* __restrict__ h0p,
                                              const float* __restrict__ b0,
                                              const float* __restrict__ lng,
                                              const float* __restrict__ lnb,
                                              const float* __restrict__ W1,
                                              const float* __restrict__ asrc1,
                                              const float* __restrict__ adst1,
                                              ushort* __restrict__ h1b,
                                              float* __restrict__ as1, float* __restrict__ ad1) {
  __shared__ uint gbuf[4][W * 64];  // per-wave gather landing zone (W rows x 256B)
  __shared__ float yb[4][64];       // wave-private y row for linear1 broadcasts
  int tid = threadIdx.x;
  int lane = tid & 63, wl = tid >> 6;
  int n = blockIdx.x * 4 + wl;
  int nE = cnt[n];     // already capped at BW by merge
  int items = nE + 1;  // + self item at idx == nE
  float2 ad = ad0v[n];
  float acc0 = 0.f, acc1 = 0.f, den0 = 0.f, den1 = 0.f;
  uint* gb = gbuf[wl];

  for (int w0 = 0; w0 < items; w0 += W) {
    int idx = w0 + lane;
    uint s = 0u;
    float wv0 = 0.f, wv1 = 0.f;  // padded lanes contribute exactly 0
    if (lane < W && idx < items) {
      s = (idx < nE) ? (uint)bkt[n * BW + idx] : (uint)n;  // self item
      float2 a = as0v[s];                                  // L2-resident gather
      wv0 = __expf(lrelu(a.x + ad.x));
      wv1 = __expf(lrelu(a.y + ad.y));
    }
    // issue all W gathers into LDS (no VGPR destinations)
#pragma unroll
    for (int j = 0; j < W; ++j) {
      uint sx = (uint)__builtin_amdgcn_readlane((int)s, j);  // SGPR row index
      __builtin_amdgcn_global_load_lds((const uint*)(h0p + sx * 64u + (uint)lane),
                                       gb + j * 64, 4, 0, 0);
    }
    asm volatile("s_waitcnt vmcnt(0)" ::: "memory");
    __builtin_amdgcn_sched_barrier(0);
#pragma unroll
    for (int j = 0; j < W; ++j) {
      float w0j = __uint_as_float(
          (uint)__builtin_amdgcn_readlane((int)__float_as_uint(wv0), j));
      float w1j = __uint_as_float(
          (uint)__builtin_amdgcn_readlane((int)__float_as_uint(wv1), j));
      uint h = gb[j * 64 + lane];
      acc0 = fmaf(w0j, b2f_lo(h), acc0); den0 += w0j;
      acc1 = fmaf(w1j, b2f_hi(h), acc1); den1 += w1j;
    }
    asm volatile("s_waitcnt lgkmcnt(0)" ::: "memory");  // drain LDS reads before gbuf reuse
    __builtin_amdgcn_sched_barrier(0);
  }

  float v = 0.5f * (acc0 / den0 + acc1 / den1) + b0[lane];
  // LayerNorm across the 64 channels (one wave)
  float mu = v;
#pragma unroll
  for (int o = 32; o >= 1; o >>= 1) mu += __shfl_xor(mu, o, 64);
  mu *= (1.0f / 64.0f);
  float d = v - mu;
  float vr = d * d;
#pragma unroll
  for (int o = 32; o >= 1; o >>= 1) vr += __shfl_xor(vr, o, 64);
  vr *= (1.0f / 64.0f);
  float y = d * rsqrtf(vr + 1e-5f) * lng[lane] + lnb[lane];
  // ELU
  y = y > 0.f ? y : expm1f(y);
  // linear1 via LDS broadcast: h1[c] = sum_k y_k * W1[k,c], 4 partial accumulators.
  yb[wl][lane] = y;
  const float4* yp = (const float4*)yb[wl];
  float q0 = 0.f, q1 = 0.f, q2 = 0.f, q3 = 0.f;
#pragma unroll
  for (int k4 = 0; k4 < 16; ++k4) {
    float4 yy = yp[k4];  // wave-uniform address -> LDS broadcast, conflict-free
    q0 = fmaf(yy.x, W1[(4 * k4 + 0) * 64 + lane], q0);
    q1 = fmaf(yy.y, W1[(4 * k4 + 1) * 64 + lane], q1);
    q2 = fmaf(yy.z, W1[(4 * k4 + 2) * 64 + lane], q2);
    q3 = fmaf(yy.w, W1[(4 * k4 + 3) * 64 + lane], q3);
  }
  float h1v = (q0 + q1) + (q2 + q3);
  h1b[n * 64 + lane] = (ushort)f2b(h1v);
  float sa = h1v * asrc1[lane];
  float sdv = h1v * adst1[lane];
#pragma unroll
  for (int o = 32; o >= 1; o >>= 1) {
    sa += __shfl_xor(sa, o, 64);
    sdv += __shfl_xor(sdv, o, 64);
  }
  if (lane == 0) {
    as1[n] = sa;
    ad1[n] = sdv;
  }
}

// ---------------- Layer 1 aggregate -> output (R18 form) ----------------

__global__ __launch_bounds__(256) void k_agg1(const int* __restrict__ cnt,
                                              const ushort* __restrict__ bkt,
                                              const ushort* __restrict__ h1b,
                                              const float* __restrict__ as1,
                                              const float* __restrict__ ad1,
                                              const float* __restrict__ b1,
                                              float* __restrict__ out) {
  __shared__ uint gbuf[4][W * 64];
  int tid = threadIdx.x;
  int lane = tid & 63, wl = tid >> 6;
  int n = blockIdx.x * 4 + wl;
  int nE = cnt[n];
  int items = nE + 1;
  float adv = ad1[n];
  float acc = 0.f, den = 0.f;
  uint* gb = gbuf[wl];
  const ushort* gbs = (const ushort*)gb;

  for (int w0 = 0; w0 < items; w0 += W) {
    int idx = w0 + lane;
    uint s = 0u;
    float wv = 0.f;
    if (lane < W && idx < items) {
      s = (idx < nE) ? (uint)bkt[n * BW + idx] : (uint)n;
      wv = __expf(lrelu(as1[s] + adv));  // one exp per lane, not per edge
    }
    uint hl = lane & 31;  // lanes 32-63 duplicate lanes 0-31 (same cache lines)
#pragma unroll
    for (int j = 0; j < W; ++j) {
      uint sx = (uint)__builtin_amdgcn_readlane((int)s, j);
      __builtin_amdgcn_global_load_lds((const uint*)(h1b + sx * 64u) + hl,
                                       gb + j * 64, 4, 0, 0);
    }
    asm volatile("s_waitcnt vmcnt(0)" ::: "memory");
    __builtin_amdgcn_sched_barrier(0);
#pragma unroll
    for (int j = 0; j < W; ++j) {
      float wj = __uint_as_float(
          (uint)__builtin_amdgcn_readlane((int)__float_as_uint(wv), j));
      uint hh = (uint)gbs[j * 128 + lane];  // valid first 128B of the slot
      acc = fmaf(wj, __uint_as_float(hh << 16), acc);
      den += wj;
    }
    asm volatile("s_waitcnt lgkmcnt(0)" ::: "memory");
    __builtin_amdgcn_sched_barrier(0);
  }
  out[n * 64 + lane] = acc / den + b1[lane];
}

// ---------------- host ----------------

extern "C" void kernel_launch(void* const* d_in, const int* in_sizes, int n_in,
                              void* d_out, int out_size, void* d_ws, size_t ws_size,
                              hipStream_t stream) {
  const float* x    = (const float*)d_in[0];
  const int*   ei   = (const int*)d_in[1];
  const float* emb  = (const float*)d_in[2];
  const float* W0   = (const float*)d_in[3];
  const float* as0w = (const float*)d_in[4];
  const float* ad0w = (const float*)d_in[5];
  const float* b0   = (const float*)d_in[6];
  const float* lng  = (const float*)d_in[7];
  const float* lnb  = (const float*)d_in[8];
  const float* W1   = (const float*)d_in[9];
  const float* as1w = (const float*)d_in[10];
  const float* ad1w = (const float*)d_in[11];
  const float* b1   = (const float*)d_in[12];
  float* out = (float*)d_out;

  // workspace layout (~41 MB): XCD-private bkt/cnt + compact bktc/cntc
  ushort* bkt = (ushort*)d_ws;                      // 8*N*BWX ushorts = 12.8MB
  int* cnt    = (int*)(bkt + NXCD * N_NODES * BWX); // 8*N ints = 1.6MB
  ushort* bktc = (ushort*)(cnt + NXCD * N_NODES);   // N*BW ushorts = 4.8MB
  int* cntc   = (int*)(bktc + N_NODES * BW);        // N ints
  float* as0 = (float*)(cntc + N_NODES);            // N*2 (float2 per node)
  float* ad0 = as0 + N_NODES * 2;                   // N*2
  float* as1 = ad0 + N_NODES * 2;                   // N
  float* ad1 = as1 + N_NODES;                       // N
  uint* h0p  = (uint*)(ad1 + N_NODES);              // N*64 (bf16x2 packed) = 12.8MB
  ushort* h1b = (ushort*)(h0p + N_NODES * 64);      // N*64 bf16 = 6.4MB

  hipMemsetAsync(cnt, 0, NXCD * N_NODES * sizeof(int), stream);
  k_bfill<<<EDGE_BLOCKS, 256, 0, stream>>>(ei, cnt, bkt);
  k_node0<<<NODE0_BLOCKS + MERGE_BLOCKS, 256, 0, stream>>>(x, emb, W0, as0w, ad0w, cnt, bkt,
                                                           (ushort*)h0p, as0, ad0, cntc, bktc);
  k_agg0<<<N_NODES / 4, 256, 0, stream>>>(cntc, bktc, (const float2*)as0, (const float2*)ad0,
                                          h0p, b0, lng, lnb, W1, as1w, ad1w, h1b, as1, ad1);
  k_agg1<<<N_NODES / 4, 256, 0, stream>>>(cntc, bktc, h1b, as1, ad1, b1, out);
}